// Round 4
// baseline (464.344 us; speedup 1.0000x reference)
//
#include <hip/hip_runtime.h>

// B=8, S=512, D=1024, H=16, DK=64
typedef __bf16 bf16x8 __attribute__((ext_vector_type(8)));
typedef float  f32x4  __attribute__((ext_vector_type(4)));

__device__ __forceinline__ unsigned short f2bf(float f) {
  union { float f; unsigned u; } x; x.f = f;
  unsigned r = (x.u + 0x7FFFu + ((x.u >> 16) & 1u)) >> 16;  // RNE
  return (unsigned short)r;
}

__device__ __forceinline__ void gload_lds16(const void* g, void* l) {
  __builtin_amdgcn_global_load_lds((__attribute__((address_space(1))) void*)g,
                                   (__attribute__((address_space(3))) void*)l,
                                   16, 0, 0);
}

// ================= fused prep =================
// blocks [0,8192):      conv  query/key_in fp32 -> bf16 (float4 streams)
// blocks [8192,10240):  wtrans Wq/Wk (K,N) -> (N,K) bf16
// blocks [10240,10496): bitmask mask int32 -> 64-bit ballots
// blocks [10496,10752): prep_u: per (bh, d-half) recompute asp->aw (cheap,
//                       hidden under conv streaming), c (id&1==0), u rows
__global__ __launch_bounds__(256)
void prep_fused_kernel(const float* __restrict__ query, const float* __restrict__ key_in,
                       const float* __restrict__ Wq, const float* __restrict__ Wk,
                       const float* __restrict__ aspect, const float* __restrict__ Wd,
                       const float* __restrict__ bd, const float* __restrict__ weight_m,
                       const float* __restrict__ bk, const int* __restrict__ mask,
                       unsigned short* __restrict__ Aq, unsigned short* __restrict__ Ak,
                       unsigned short* __restrict__ Wqt, unsigned short* __restrict__ Wkt,
                       float* __restrict__ u_out, float* __restrict__ c_out,
                       unsigned long long* __restrict__ mb) {
  __shared__ __align__(16) char smem[2112];
  const int bx = blockIdx.x, tid = threadIdx.x;
  if (bx < 8192) {
    int i = bx * 256 + tid;
    if (i < 1048576) {
      float4 x = ((const float4*)query)[i];
      ushort4 y; y.x = f2bf(x.x); y.y = f2bf(x.y); y.z = f2bf(x.z); y.w = f2bf(x.w);
      ((ushort4*)Aq)[i] = y;
    } else {
      int j = i - 1048576;
      float4 x = ((const float4*)key_in)[j];
      ushort4 y; y.x = f2bf(x.x); y.y = f2bf(x.y); y.z = f2bf(x.z); y.w = f2bf(x.w);
      ((ushort4*)Ak)[j] = y;
    }
  } else if (bx < 10240) {
    int t = bx - 8192;
    const float* W = (t >> 10) ? Wk : Wq;
    unsigned short* Wt = (t >> 10) ? Wkt : Wqt;
    int tile_id = t & 1023;
    int k0 = (tile_id & 31) * 32, n0 = (tile_id >> 5) * 32;
    int tx = tid & 31, ty = tid >> 5;
    unsigned short (*tile)[33] = (unsigned short (*)[33])smem;
    #pragma unroll
    for (int i = 0; i < 4; ++i) {
      int k = ty + i * 8;
      tile[k][tx] = f2bf(W[(size_t)(k0 + k) * 1024 + n0 + tx]);
    }
    __syncthreads();
    #pragma unroll
    for (int i = 0; i < 4; ++i) {
      int n = ty + i * 8;
      Wt[(size_t)(n0 + n) * 1024 + k0 + tx] = tile[tx][n];
    }
  } else if (bx < 10496) {
    int t = bx - 10240;
    int gw = (t * 256 + tid) >> 6, lane = tid & 63;
    for (int row = gw; row < 4096; row += 1024) {
      const int* mr = mask + (size_t)row * 512;
      unsigned long long* dst = mb + (size_t)row * 8;
      #pragma unroll
      for (int it = 0; it < 8; ++it) {
        int m = mr[it * 64 + lane];
        unsigned long long bb = __ballot(m != 0);
        if (lane == 0) dst[it] = bb;
      }
    }
  } else {
    int id = bx - 10496;                // 0..255
    int bh = id >> 1, b = bh >> 4, h = bh & 15;
    int dbase = (id & 1) * 512;
    int e = tid & 63, g = tid >> 6;
    float* part  = (float*)smem;        // 256 floats
    float* asp_s = part + 256;          // 64
    float* aw_s  = asp_s + 64;          // 64
    const float* arow = aspect + (size_t)b * 1024;
    float acc = 0.f;
    for (int d = g * 256; d < g * 256 + 256; ++d)
      acc += arow[d] * Wd[(size_t)d * 64 + e];
    part[g * 64 + e] = acc;
    __syncthreads();
    if (tid < 64)
      asp_s[tid] = bd[tid] + part[tid] + part[64 + tid] + part[128 + tid] + part[192 + tid];
    __syncthreads();
    if (tid < 64) {
      const float* wm = weight_m + (size_t)h * 4096;
      float aw = 0.f;
      #pragma unroll 8
      for (int d = 0; d < 64; ++d) aw += asp_s[d] * wm[d * 64 + tid];
      aw_s[tid] = aw;
    }
    __syncthreads();
    float awl = aw_s[e];
    if ((id & 1) == 0 && g == 0) {
      float s = bk[h * 64 + e] * awl;
      #pragma unroll
      for (int off = 32; off >= 1; off >>= 1) s += __shfl_xor(s, off, 64);
      if (e == 0) c_out[bh] = s;
    }
    const float* wkcol = Wk + h * 64 + e;
    #pragma unroll 2
    for (int it = 0; it < 32; ++it) {
      int d0 = dbase + g * 128 + it * 4;
      float s0 = wkcol[(size_t)d0 * 1024] * awl;
      float s1 = wkcol[(size_t)(d0 + 1) * 1024] * awl;
      float s2 = wkcol[(size_t)(d0 + 2) * 1024] * awl;
      float s3 = wkcol[(size_t)(d0 + 3) * 1024] * awl;
      #pragma unroll
      for (int off = 32; off >= 1; off >>= 1) {
        s0 += __shfl_xor(s0, off, 64);
        s1 += __shfl_xor(s1, off, 64);
        s2 += __shfl_xor(s2, off, 64);
        s3 += __shfl_xor(s3, off, 64);
      }
      if (e == 0) {
        float4 uo = {s0, s1, s2, s3};
        *(float4*)(u_out + (size_t)bh * 1024 + d0) = uo;
      }
    }
  }
}

// ---- v[b,h,t] = tanh(key_in[b,t,:].u[b,h,:] + c[b,h] + bias_m), fp32 exact ----
__global__ __launch_bounds__(256)
void v_kernel(const float* __restrict__ key_in, const float* __restrict__ u,
              const float* __restrict__ c, const float* __restrict__ bias_m,
              float* __restrict__ v) {
  __shared__ float ks_[8][1024];  // 32 KB
  int b = blockIdx.y, t0 = blockIdx.x * 8;
  int tid = threadIdx.x, wid = tid >> 6, lane = tid & 63;
  const float4* ksrc = (const float4*)(key_in + ((size_t)b * 512 + t0) * 1024);
  float4* kdst = (float4*)&ks_[0][0];
  for (int i = tid; i < 2048; i += 256) kdst[i] = ksrc[i];
  __syncthreads();
  const float* ub = u + (size_t)b * 16384;
  int r0 = wid * 2;
  float acc0[16] = {}, acc1[16] = {};
  for (int i = 0; i < 16; ++i) {
    int col = lane + 64 * i;
    float kv0 = ks_[r0][col], kv1 = ks_[r0 + 1][col];
    #pragma unroll
    for (int h = 0; h < 16; ++h) {
      float uv = ub[h * 1024 + col];
      acc0[h] += kv0 * uv;
      acc1[h] += kv1 * uv;
    }
  }
  float cb = bias_m[0];
  #pragma unroll
  for (int h = 0; h < 16; ++h) {
    float a0 = acc0[h], a1 = acc1[h];
    #pragma unroll
    for (int off = 32; off >= 1; off >>= 1) {
      a0 += __shfl_xor(a0, off, 64);
      a1 += __shfl_xor(a1, off, 64);
    }
    if (lane == h) {
      int bh = b * 16 + h;
      float cc = c[bh] + cb;
      v[(size_t)bh * 512 + t0 + r0]     = tanhf(a0 + cc);
      v[(size_t)bh * 512 + t0 + r0 + 1] = tanhf(a1 + cc);
    }
  }
}

// ---- a_sc fill (lastocc computed inline), nontemporal float4 writes ----
__global__ void asc_kernel(const float* __restrict__ v, const int* __restrict__ ids,
                           float* __restrict__ out) {
  size_t i4 = (size_t)blockIdx.x * 256 + threadIdx.x;  // float4 index
  int t0 = (int)(i4 & 127) * 4;
  int s  = (int)(i4 >> 7) & 511;
  int bh = (int)(i4 >> 16);
  int b  = bh >> 4;
  int i0 = ids[b * 4], i1 = ids[b * 4 + 1], i2 = ids[b * 4 + 2], i3 = ids[b * 4 + 3];
  #define LASTOF(t) ((i3==(t))?3:(i2==(t))?2:(i1==(t))?1:(i0==(t))?0:-1)
  int ls  = LASTOF(s);
  int lt0 = LASTOF(t0), lt1 = LASTOF(t0+1), lt2 = LASTOF(t0+2), lt3 = LASTOF(t0+3);
  #undef LASTOF
  const float* vrow = v + (size_t)bh * 512;
  float vs = vrow[s];
  float4 vt = *(const float4*)(vrow + t0);
  f32x4 o;
  o[0] = (lt0 >= 0 && lt0 >= ls) ? vs : vt.x;
  o[1] = (lt1 >= 0 && lt1 >= ls) ? vs : vt.y;
  o[2] = (lt2 >= 0 && lt2 >= ls) ? vs : vt.z;
  o[3] = (lt3 >= 0 && lt3 >= ls) ? vs : vt.w;
  __builtin_nontemporal_store(o, ((f32x4*)out) + i4);
}

// ---- bf16 MFMA GEMM, BK=64, XOR-swizzled LDS; grid (32 m, 8 n, 2 gemms) ----
__global__ __launch_bounds__(256, 2)
void gemm_kernel(const unsigned short* __restrict__ Aq, const unsigned short* __restrict__ Ak,
                 const unsigned short* __restrict__ Bq, const unsigned short* __restrict__ Bk,
                 const float* __restrict__ bq, const float* __restrict__ bk,
                 unsigned short* __restrict__ qb, unsigned short* __restrict__ kb) {
  const unsigned short* A  = blockIdx.z ? Ak : Aq;
  const unsigned short* Bt = blockIdx.z ? Bk : Bq;
  const float* bias = blockIdx.z ? bk : bq;
  unsigned short* out = blockIdx.z ? kb : qb;
  const int m0 = blockIdx.x * 128, n0 = blockIdx.y * 128;
  __shared__ __align__(16) unsigned short As[128 * 64];  // 16 KB
  __shared__ __align__(16) unsigned short Bs[128 * 64];
  const int tid = threadIdx.x, wid = tid >> 6, lane = tid & 63;
  const int wr = wid >> 1, wc = wid & 1;
  const int quad = lane >> 4, l15 = lane & 15;
  const int srw = lane >> 3;
  const int jcol = ((lane & 7) ^ srw) * 8;
  const int p0 = (quad ^ (l15 & 7)) * 8;
  f32x4 acc[4][4] = {};
  for (int k0 = 0; k0 < 1024; k0 += 64) {
    #pragma unroll
    for (int i = 0; i < 4; ++i) {
      int r = wid * 32 + i * 8 + srw;
      gload_lds16(A  + (size_t)(m0 + r) * 1024 + k0 + jcol, As + (wid * 32 + i * 8) * 64);
      gload_lds16(Bt + (size_t)(n0 + r) * 1024 + k0 + jcol, Bs + (wid * 32 + i * 8) * 64);
    }
    __syncthreads();
    bf16x8 af[4][2], bfr[4][2];
    #pragma unroll
    for (int mi = 0; mi < 4; ++mi) {
      const unsigned short* base = As + (wr * 64 + mi * 16 + l15) * 64;
      af[mi][0] = *(const bf16x8*)(base + p0);
      af[mi][1] = *(const bf16x8*)(base + (p0 ^ 32));
    }
    #pragma unroll
    for (int ni = 0; ni < 4; ++ni) {
      const unsigned short* base = Bs + (wc * 64 + ni * 16 + l15) * 64;
      bfr[ni][0] = *(const bf16x8*)(base + p0);
      bfr[ni][1] = *(const bf16x8*)(base + (p0 ^ 32));
    }
    #pragma unroll
    for (int mi = 0; mi < 4; ++mi)
      #pragma unroll
      for (int ni = 0; ni < 4; ++ni) {
        acc[mi][ni] = __builtin_amdgcn_mfma_f32_16x16x32_bf16(af[mi][0], bfr[ni][0], acc[mi][ni], 0, 0, 0);
        acc[mi][ni] = __builtin_amdgcn_mfma_f32_16x16x32_bf16(af[mi][1], bfr[ni][1], acc[mi][ni], 0, 0, 0);
      }
    __syncthreads();
  }
  #pragma unroll
  for (int mi = 0; mi < 4; ++mi) {
    #pragma unroll
    for (int ni = 0; ni < 4; ++ni) {
      const int n = n0 + wc * 64 + ni * 16 + l15;
      const int hh = n >> 6, dk = n & 63;
      const float bv = bias[n];
      #pragma unroll
      for (int r = 0; r < 4; ++r) {
        const int m = m0 + wr * 64 + mi * 16 + quad * 4 + r;
        const int bb = m >> 9, ss = m & 511;
        out[(((size_t)bb * 16 + hh) * 512 + ss) * 64 + dk] = f2bf(acc[mi][ni][r] + bv);
      }
    }
  }
}

// ---- scores + bitmask + softmax; single-stage 64 KB k slab, one barrier ----
__global__ __launch_bounds__(256, 2)
void attn_kernel(const unsigned short* __restrict__ qb, const unsigned short* __restrict__ kb,
                 const unsigned* __restrict__ mbits, float* __restrict__ attn) {
  __shared__ __align__(16) unsigned short ks[512 * 64];  // 64 KB
  __shared__ __align__(16) unsigned short qs[64 * 64];   // 8 KB
  const int bh = blockIdx.x, b = bh >> 4;
  const int s0 = blockIdx.y * 64;
  const int tid = threadIdx.x, wid = tid >> 6, lane = tid & 63;
  const int quad = lane >> 4, l15 = lane & 15;
  const int srw = lane >> 3;
  const int j8 = ((lane & 7) ^ srw) * 8;
  const int p0 = (quad ^ (l15 & 7)) * 8;
  const unsigned short* kslab = kb + (size_t)bh * 512 * 64;
  const unsigned short* qslab = qb + ((size_t)bh * 512 + s0) * 64;
  #pragma unroll
  for (int i = 0; i < 2; ++i)
    gload_lds16(qslab + (wid * 2 + i) * 512 + srw * 64 + j8, qs + (wid * 2 + i) * 512);
  #pragma unroll
  for (int i = 0; i < 16; ++i)
    gload_lds16(kslab + (wid * 16 + i) * 512 + srw * 64 + j8, ks + (wid * 16 + i) * 512);
  __syncthreads();
  const unsigned short* qbase = qs + (wid * 16 + l15) * 64;
  bf16x8 af0 = *(const bf16x8*)(qbase + p0);
  bf16x8 af1 = *(const bf16x8*)(qbase + (p0 ^ 32));
  f32x4 acc[32];
  #pragma unroll
  for (int tile = 0; tile < 32; ++tile) {
    const unsigned short* kbase = ks + (tile * 16 + l15) * 64;
    bf16x8 b0 = *(const bf16x8*)(kbase + p0);
    bf16x8 b1 = *(const bf16x8*)(kbase + (p0 ^ 32));
    f32x4 a = {0.f, 0.f, 0.f, 0.f};
    a = __builtin_amdgcn_mfma_f32_16x16x32_bf16(af0, b0, a, 0, 0, 0);
    a = __builtin_amdgcn_mfma_f32_16x16x32_bf16(af1, b1, a, 0, 0, 0);
    acc[tile] = a;
  }
  const size_t srow = (size_t)s0 + wid * 16 + quad * 4;
  const unsigned* mrow = mbits + ((size_t)b * 512 + srow) * 16;
  float mx[4] = {-3.0e38f, -3.0e38f, -3.0e38f, -3.0e38f};
  #pragma unroll
  for (int tp = 0; tp < 16; ++tp) {
    #pragma unroll
    for (int r = 0; r < 4; ++r) {
      unsigned m = mrow[(size_t)r * 16 + tp];
      float sc0 = acc[2 * tp][r] * 0.125f;
      float sc1 = acc[2 * tp + 1][r] * 0.125f;
      sc0 = ((m >> l15) & 1u) ? sc0 : -1.0e9f;
      sc1 = ((m >> (16 + l15)) & 1u) ? sc1 : -1.0e9f;
      acc[2 * tp][r] = sc0;
      acc[2 * tp + 1][r] = sc1;
      mx[r] = fmaxf(mx[r], fmaxf(sc0, sc1));
    }
  }
  #pragma unroll
  for (int r = 0; r < 4; ++r)
    #pragma unroll
    for (int off = 1; off < 16; off <<= 1)
      mx[r] = fmaxf(mx[r], __shfl_xor(mx[r], off, 64));
  float sm[4] = {0.f, 0.f, 0.f, 0.f};
  #pragma unroll
  for (int tile = 0; tile < 32; ++tile)
    #pragma unroll
    for (int r = 0; r < 4; ++r) {
      float e = __expf(acc[tile][r] - mx[r]);
      acc[tile][r] = e;
      sm[r] += e;
    }
  #pragma unroll
  for (int r = 0; r < 4; ++r) {
    #pragma unroll
    for (int off = 1; off < 16; off <<= 1)
      sm[r] += __shfl_xor(sm[r], off, 64);
    sm[r] = 1.0f / sm[r];
  }
  float* obase = attn + ((size_t)bh * 512 + srow) * 512 + l15;
  #pragma unroll
  for (int r = 0; r < 4; ++r)
    #pragma unroll
    for (int tile = 0; tile < 32; ++tile)
      __builtin_nontemporal_store(acc[tile][r] * sm[r], &obase[(size_t)r * 512 + tile * 16]);
}

extern "C" void kernel_launch(void* const* d_in, const int* in_sizes, int n_in,
                              void* d_out, int out_size, void* d_ws, size_t ws_size,
                              hipStream_t stream) {
  const float* query    = (const float*)d_in[0];
  const float* key_in   = (const float*)d_in[1];
  const int*   mask     = (const int*)d_in[2];
  const float* aspect   = (const float*)d_in[3];
  const int*   a_ids    = (const int*)d_in[4];
  const float* Wq       = (const float*)d_in[5];
  const float* bq       = (const float*)d_in[6];
  const float* Wk       = (const float*)d_in[7];
  const float* bk       = (const float*)d_in[8];
  const float* Wd       = (const float*)d_in[9];
  const float* bd       = (const float*)d_in[10];
  const float* weight_m = (const float*)d_in[11];
  const float* bias_m   = (const float*)d_in[12];

  float* out_asc  = (float*)d_out;
  float* out_attn = out_asc + 33554432ull;  // B*H*S*S

  char* ws = (char*)d_ws;
  unsigned short* Aq   = (unsigned short*)(ws);                 // 8 MB  bf16 query
  unsigned short* Ak   = (unsigned short*)(ws + 8388608);       // 8 MB  bf16 key_in
  unsigned short* Wqt  = (unsigned short*)(ws + 16777216);      // 2 MB  bf16 Wq^T
  unsigned short* Wkt  = (unsigned short*)(ws + 18874368);      // 2 MB  bf16 Wk^T
  unsigned short* qbuf = (unsigned short*)(ws + 20971520);      // 8 MB  q (B,H,S,DK)
  unsigned short* kbuf = (unsigned short*)(ws + 29360128);      // 8 MB  k (B,H,S,DK)
  float* u   = (float*)(ws + 37748736);                         // 512 KB
  float* c   = (float*)(ws + 38273024);                         // 4 KB pad
  float* v   = (float*)(ws + 38277120);                         // 256 KB
  unsigned long long* mb = (unsigned long long*)(ws + 38539264);// 256 KB bitmask

  prep_fused_kernel<<<dim3(10752), dim3(256), 0, stream>>>(
      query, key_in, Wq, Wk, aspect, Wd, bd, weight_m, bk, mask,
      Aq, Ak, Wqt, Wkt, u, c, mb);
  gemm_kernel<<<dim3(32, 8, 2), dim3(256), 0, stream>>>(Aq, Ak, Wqt, Wkt, bq, bk, qbuf, kbuf);
  v_kernel<<<dim3(64, 8), dim3(256), 0, stream>>>(key_in, u, c, bias_m, v);
  asc_kernel<<<dim3(32768), dim3(256), 0, stream>>>(v, a_ids, out_asc);
  attn_kernel<<<dim3(128, 8), dim3(256), 0, stream>>>(qbuf, kbuf, (const unsigned*)mb, out_attn);
}

// Round 5
// 405.570 us; speedup vs baseline: 1.1449x; 1.1449x over previous
//
#include <hip/hip_runtime.h>

// B=8, S=512, D=1024, H=16, DK=64
typedef __bf16 bf16x8 __attribute__((ext_vector_type(8)));
typedef float  f32x4  __attribute__((ext_vector_type(4)));

__device__ __forceinline__ unsigned short f2bf(float f) {
  union { float f; unsigned u; } x; x.f = f;
  unsigned r = (x.u + 0x7FFFu + ((x.u >> 16) & 1u)) >> 16;  // RNE
  return (unsigned short)r;
}

__device__ __forceinline__ void gload_lds16(const void* g, void* l) {
  __builtin_amdgcn_global_load_lds((__attribute__((address_space(1))) void*)g,
                                   (__attribute__((address_space(3))) void*)l,
                                   16, 0, 0);
}

// ================= fused prep (latency-bound blocks FIRST) =================
// blocks [0,256):       prep_u: per (bh, d-half) asp->aw (recomputed), c, u rows
// blocks [256,512):     bitmask mask int32 -> 64-bit ballots
// blocks [512,2560):    wtrans Wq/Wk (K,N) -> (N,K) bf16
// blocks [2560,10752):  conv query/key_in fp32 -> bf16 (float4 streams)
__global__ __launch_bounds__(256)
void prep_fused_kernel(const float* __restrict__ query, const float* __restrict__ key_in,
                       const float* __restrict__ Wq, const float* __restrict__ Wk,
                       const float* __restrict__ aspect, const float* __restrict__ Wd,
                       const float* __restrict__ bd, const float* __restrict__ weight_m,
                       const float* __restrict__ bk, const int* __restrict__ mask,
                       unsigned short* __restrict__ Aq, unsigned short* __restrict__ Ak,
                       unsigned short* __restrict__ Wqt, unsigned short* __restrict__ Wkt,
                       float* __restrict__ u_out, float* __restrict__ c_out,
                       unsigned long long* __restrict__ mb) {
  __shared__ __align__(16) char smem[2112];
  const int bx = blockIdx.x, tid = threadIdx.x;
  if (bx >= 2560) {
    int i = (bx - 2560) * 256 + tid;
    if (i < 1048576) {
      float4 x = ((const float4*)query)[i];
      ushort4 y; y.x = f2bf(x.x); y.y = f2bf(x.y); y.z = f2bf(x.z); y.w = f2bf(x.w);
      ((ushort4*)Aq)[i] = y;
    } else {
      int j = i - 1048576;
      float4 x = ((const float4*)key_in)[j];
      ushort4 y; y.x = f2bf(x.x); y.y = f2bf(x.y); y.z = f2bf(x.z); y.w = f2bf(x.w);
      ((ushort4*)Ak)[j] = y;
    }
  } else if (bx >= 512) {
    int t = bx - 512;
    const float* W = (t >> 10) ? Wk : Wq;
    unsigned short* Wt = (t >> 10) ? Wkt : Wqt;
    int tile_id = t & 1023;
    int k0 = (tile_id & 31) * 32, n0 = (tile_id >> 5) * 32;
    int tx = tid & 31, ty = tid >> 5;
    unsigned short (*tile)[33] = (unsigned short (*)[33])smem;
    #pragma unroll
    for (int i = 0; i < 4; ++i) {
      int k = ty + i * 8;
      tile[k][tx] = f2bf(W[(size_t)(k0 + k) * 1024 + n0 + tx]);
    }
    __syncthreads();
    #pragma unroll
    for (int i = 0; i < 4; ++i) {
      int n = ty + i * 8;
      Wt[(size_t)(n0 + n) * 1024 + k0 + tx] = tile[tx][n];
    }
  } else if (bx >= 256) {
    int t = bx - 256;
    int gw = (t * 256 + tid) >> 6, lane = tid & 63;
    for (int row = gw; row < 4096; row += 1024) {
      const int* mr = mask + (size_t)row * 512;
      unsigned long long* dst = mb + (size_t)row * 8;
      #pragma unroll
      for (int it = 0; it < 8; ++it) {
        int m = mr[it * 64 + lane];
        unsigned long long bb = __ballot(m != 0);
        if (lane == 0) dst[it] = bb;
      }
    }
  } else {
    int id = bx;                        // 0..255
    int bh = id >> 1, b = bh >> 4, h = bh & 15;
    int dbase = (id & 1) * 512;
    int e = tid & 63, g = tid >> 6;
    float* part  = (float*)smem;        // 256 floats
    float* asp_s = part + 256;          // 64
    float* aw_s  = asp_s + 64;          // 64
    const float* arow = aspect + (size_t)b * 1024;
    float acc = 0.f;
    for (int d = g * 256; d < g * 256 + 256; ++d)
      acc += arow[d] * Wd[(size_t)d * 64 + e];
    part[g * 64 + e] = acc;
    __syncthreads();
    if (tid < 64)
      asp_s[tid] = bd[tid] + part[tid] + part[64 + tid] + part[128 + tid] + part[192 + tid];
    __syncthreads();
    if (tid < 64) {
      const float* wm = weight_m + (size_t)h * 4096;
      float aw = 0.f;
      #pragma unroll 8
      for (int d = 0; d < 64; ++d) aw += asp_s[d] * wm[d * 64 + tid];
      aw_s[tid] = aw;
    }
    __syncthreads();
    float awl = aw_s[e];
    if ((id & 1) == 0 && g == 0) {
      float s = bk[h * 64 + e] * awl;
      #pragma unroll
      for (int off = 32; off >= 1; off >>= 1) s += __shfl_xor(s, off, 64);
      if (e == 0) c_out[bh] = s;
    }
    const float* wkcol = Wk + h * 64 + e;
    #pragma unroll 2
    for (int it = 0; it < 32; ++it) {
      int d0 = dbase + g * 128 + it * 4;
      float s0 = wkcol[(size_t)d0 * 1024] * awl;
      float s1 = wkcol[(size_t)(d0 + 1) * 1024] * awl;
      float s2 = wkcol[(size_t)(d0 + 2) * 1024] * awl;
      float s3 = wkcol[(size_t)(d0 + 3) * 1024] * awl;
      #pragma unroll
      for (int off = 32; off >= 1; off >>= 1) {
        s0 += __shfl_xor(s0, off, 64);
        s1 += __shfl_xor(s1, off, 64);
        s2 += __shfl_xor(s2, off, 64);
        s3 += __shfl_xor(s3, off, 64);
      }
      if (e == 0) {
        float4 uo = {s0, s1, s2, s3};
        *(float4*)(u_out + (size_t)bh * 1024 + d0) = uo;
      }
    }
  }
}

// ---- v[b,h,t] = tanh(key_in[b,t,:].u[b,h,:] + c[b,h] + bias_m), fp32 exact ----
__global__ __launch_bounds__(256)
void v_kernel(const float* __restrict__ key_in, const float* __restrict__ u,
              const float* __restrict__ c, const float* __restrict__ bias_m,
              float* __restrict__ v) {
  __shared__ float ks_[8][1024];  // 32 KB
  int b = blockIdx.y, t0 = blockIdx.x * 8;
  int tid = threadIdx.x, wid = tid >> 6, lane = tid & 63;
  const float4* ksrc = (const float4*)(key_in + ((size_t)b * 512 + t0) * 1024);
  float4* kdst = (float4*)&ks_[0][0];
  for (int i = tid; i < 2048; i += 256) kdst[i] = ksrc[i];
  __syncthreads();
  const float* ub = u + (size_t)b * 16384;
  int r0 = wid * 2;
  float acc0[16] = {}, acc1[16] = {};
  for (int i = 0; i < 16; ++i) {
    int col = lane + 64 * i;
    float kv0 = ks_[r0][col], kv1 = ks_[r0 + 1][col];
    #pragma unroll
    for (int h = 0; h < 16; ++h) {
      float uv = ub[h * 1024 + col];
      acc0[h] += kv0 * uv;
      acc1[h] += kv1 * uv;
    }
  }
  float cb = bias_m[0];
  #pragma unroll
  for (int h = 0; h < 16; ++h) {
    float a0 = acc0[h], a1 = acc1[h];
    #pragma unroll
    for (int off = 32; off >= 1; off >>= 1) {
      a0 += __shfl_xor(a0, off, 64);
      a1 += __shfl_xor(a1, off, 64);
    }
    if (lane == h) {
      int bh = b * 16 + h;
      float cc = c[bh] + cb;
      v[(size_t)bh * 512 + t0 + r0]     = tanhf(a0 + cc);
      v[(size_t)bh * 512 + t0 + r0 + 1] = tanhf(a1 + cc);
    }
  }
}

// ---- a_sc fill (lastocc computed inline), nontemporal float4 writes ----
__global__ void asc_kernel(const float* __restrict__ v, const int* __restrict__ ids,
                           float* __restrict__ out) {
  size_t i4 = (size_t)blockIdx.x * 256 + threadIdx.x;  // float4 index
  int t0 = (int)(i4 & 127) * 4;
  int s  = (int)(i4 >> 7) & 511;
  int bh = (int)(i4 >> 16);
  int b  = bh >> 4;
  int i0 = ids[b * 4], i1 = ids[b * 4 + 1], i2 = ids[b * 4 + 2], i3 = ids[b * 4 + 3];
  #define LASTOF(t) ((i3==(t))?3:(i2==(t))?2:(i1==(t))?1:(i0==(t))?0:-1)
  int ls  = LASTOF(s);
  int lt0 = LASTOF(t0), lt1 = LASTOF(t0+1), lt2 = LASTOF(t0+2), lt3 = LASTOF(t0+3);
  #undef LASTOF
  const float* vrow = v + (size_t)bh * 512;
  float vs = vrow[s];
  float4 vt = *(const float4*)(vrow + t0);
  f32x4 o;
  o[0] = (lt0 >= 0 && lt0 >= ls) ? vs : vt.x;
  o[1] = (lt1 >= 0 && lt1 >= ls) ? vs : vt.y;
  o[2] = (lt2 >= 0 && lt2 >= ls) ? vs : vt.z;
  o[3] = (lt3 >= 0 && lt3 >= ls) ? vs : vt.w;
  __builtin_nontemporal_store(o, ((f32x4*)out) + i4);
}

// ---- bf16 MFMA GEMM, BK=64, XOR-swizzled LDS; grid (32 m, 8 n, 2 gemms) ----
__global__ __launch_bounds__(256, 2)
void gemm_kernel(const unsigned short* __restrict__ Aq, const unsigned short* __restrict__ Ak,
                 const unsigned short* __restrict__ Bq, const unsigned short* __restrict__ Bk,
                 const float* __restrict__ bq, const float* __restrict__ bk,
                 unsigned short* __restrict__ qb, unsigned short* __restrict__ kb) {
  const unsigned short* A  = blockIdx.z ? Ak : Aq;
  const unsigned short* Bt = blockIdx.z ? Bk : Bq;
  const float* bias = blockIdx.z ? bk : bq;
  unsigned short* out = blockIdx.z ? kb : qb;
  const int m0 = blockIdx.x * 128, n0 = blockIdx.y * 128;
  __shared__ __align__(16) unsigned short As[128 * 64];  // 16 KB
  __shared__ __align__(16) unsigned short Bs[128 * 64];
  const int tid = threadIdx.x, wid = tid >> 6, lane = tid & 63;
  const int wr = wid >> 1, wc = wid & 1;
  const int quad = lane >> 4, l15 = lane & 15;
  const int srw = lane >> 3;
  const int jcol = ((lane & 7) ^ srw) * 8;
  const int p0 = (quad ^ (l15 & 7)) * 8;
  f32x4 acc[4][4] = {};
  for (int k0 = 0; k0 < 1024; k0 += 64) {
    #pragma unroll
    for (int i = 0; i < 4; ++i) {
      int r = wid * 32 + i * 8 + srw;
      gload_lds16(A  + (size_t)(m0 + r) * 1024 + k0 + jcol, As + (wid * 32 + i * 8) * 64);
      gload_lds16(Bt + (size_t)(n0 + r) * 1024 + k0 + jcol, Bs + (wid * 32 + i * 8) * 64);
    }
    __syncthreads();
    bf16x8 af[4][2], bfr[4][2];
    #pragma unroll
    for (int mi = 0; mi < 4; ++mi) {
      const unsigned short* base = As + (wr * 64 + mi * 16 + l15) * 64;
      af[mi][0] = *(const bf16x8*)(base + p0);
      af[mi][1] = *(const bf16x8*)(base + (p0 ^ 32));
    }
    #pragma unroll
    for (int ni = 0; ni < 4; ++ni) {
      const unsigned short* base = Bs + (wc * 64 + ni * 16 + l15) * 64;
      bfr[ni][0] = *(const bf16x8*)(base + p0);
      bfr[ni][1] = *(const bf16x8*)(base + (p0 ^ 32));
    }
    #pragma unroll
    for (int mi = 0; mi < 4; ++mi)
      #pragma unroll
      for (int ni = 0; ni < 4; ++ni) {
        acc[mi][ni] = __builtin_amdgcn_mfma_f32_16x16x32_bf16(af[mi][0], bfr[ni][0], acc[mi][ni], 0, 0, 0);
        acc[mi][ni] = __builtin_amdgcn_mfma_f32_16x16x32_bf16(af[mi][1], bfr[ni][1], acc[mi][ni], 0, 0, 0);
      }
    __syncthreads();
  }
  #pragma unroll
  for (int mi = 0; mi < 4; ++mi) {
    #pragma unroll
    for (int ni = 0; ni < 4; ++ni) {
      const int n = n0 + wc * 64 + ni * 16 + l15;
      const int hh = n >> 6, dk = n & 63;
      const float bv = bias[n];
      #pragma unroll
      for (int r = 0; r < 4; ++r) {
        const int m = m0 + wr * 64 + mi * 16 + quad * 4 + r;
        const int bb = m >> 9, ss = m & 511;
        out[(((size_t)bb * 16 + hh) * 512 + ss) * 64 + dk] = f2bf(acc[mi][ni][r] + bv);
      }
    }
  }
}

// ---- scores + bitmask + softmax; 2-stage 32 KB k staging (R3 version) ----
__global__ __launch_bounds__(256, 2)
void attn_kernel(const unsigned short* __restrict__ qb, const unsigned short* __restrict__ kb,
                 const unsigned* __restrict__ mbits, float* __restrict__ attn) {
  __shared__ __align__(16) unsigned short ks[256 * 64];  // 32 KB (half of k slab)
  __shared__ __align__(16) unsigned short qs[64 * 64];   // 8 KB
  const int bh = blockIdx.x, b = bh >> 4;
  const int s0 = blockIdx.y * 64;
  const int tid = threadIdx.x, wid = tid >> 6, lane = tid & 63;
  const int quad = lane >> 4, l15 = lane & 15;
  const int srw = lane >> 3;
  const int j8 = ((lane & 7) ^ srw) * 8;
  const int p0 = (quad ^ (l15 & 7)) * 8;
  const unsigned short* kslab = kb + (size_t)bh * 512 * 64;
  const unsigned short* qslab = qb + ((size_t)bh * 512 + s0) * 64;
  #pragma unroll
  for (int i = 0; i < 2; ++i)
    gload_lds16(qslab + (wid * 2 + i) * 512 + srw * 64 + j8, qs + (wid * 2 + i) * 512);
  #pragma unroll
  for (int i = 0; i < 8; ++i)
    gload_lds16(kslab + (wid * 8 + i) * 512 + srw * 64 + j8, ks + (wid * 8 + i) * 512);
  __syncthreads();
  const unsigned short* qbase = qs + (wid * 16 + l15) * 64;
  bf16x8 af0 = *(const bf16x8*)(qbase + p0);
  bf16x8 af1 = *(const bf16x8*)(qbase + (p0 ^ 32));
  f32x4 acc[32];
  #pragma unroll
  for (int tile = 0; tile < 16; ++tile) {
    const unsigned short* kbase = ks + (tile * 16 + l15) * 64;
    bf16x8 b0 = *(const bf16x8*)(kbase + p0);
    bf16x8 b1 = *(const bf16x8*)(kbase + (p0 ^ 32));
    f32x4 a = {0.f, 0.f, 0.f, 0.f};
    a = __builtin_amdgcn_mfma_f32_16x16x32_bf16(af0, b0, a, 0, 0, 0);
    a = __builtin_amdgcn_mfma_f32_16x16x32_bf16(af1, b1, a, 0, 0, 0);
    acc[tile] = a;
  }
  __syncthreads();
  #pragma unroll
  for (int i = 0; i < 8; ++i)
    gload_lds16(kslab + 16384 + (wid * 8 + i) * 512 + srw * 64 + j8, ks + (wid * 8 + i) * 512);
  __syncthreads();
  #pragma unroll
  for (int tile = 16; tile < 32; ++tile) {
    const unsigned short* kbase = ks + ((tile - 16) * 16 + l15) * 64;
    bf16x8 b0 = *(const bf16x8*)(kbase + p0);
    bf16x8 b1 = *(const bf16x8*)(kbase + (p0 ^ 32));
    f32x4 a = {0.f, 0.f, 0.f, 0.f};
    a = __builtin_amdgcn_mfma_f32_16x16x32_bf16(af0, b0, a, 0, 0, 0);
    a = __builtin_amdgcn_mfma_f32_16x16x32_bf16(af1, b1, a, 0, 0, 0);
    acc[tile] = a;
  }
  const size_t srow = (size_t)s0 + wid * 16 + quad * 4;
  const unsigned* mrow = mbits + ((size_t)b * 512 + srow) * 16;
  float mx[4] = {-3.0e38f, -3.0e38f, -3.0e38f, -3.0e38f};
  #pragma unroll
  for (int tp = 0; tp < 16; ++tp) {
    #pragma unroll
    for (int r = 0; r < 4; ++r) {
      unsigned m = mrow[(size_t)r * 16 + tp];
      float sc0 = acc[2 * tp][r] * 0.125f;
      float sc1 = acc[2 * tp + 1][r] * 0.125f;
      sc0 = ((m >> l15) & 1u) ? sc0 : -1.0e9f;
      sc1 = ((m >> (16 + l15)) & 1u) ? sc1 : -1.0e9f;
      acc[2 * tp][r] = sc0;
      acc[2 * tp + 1][r] = sc1;
      mx[r] = fmaxf(mx[r], fmaxf(sc0, sc1));
    }
  }
  #pragma unroll
  for (int r = 0; r < 4; ++r)
    #pragma unroll
    for (int off = 1; off < 16; off <<= 1)
      mx[r] = fmaxf(mx[r], __shfl_xor(mx[r], off, 64));
  float sm[4] = {0.f, 0.f, 0.f, 0.f};
  #pragma unroll
  for (int tile = 0; tile < 32; ++tile)
    #pragma unroll
    for (int r = 0; r < 4; ++r) {
      float e = __expf(acc[tile][r] - mx[r]);
      acc[tile][r] = e;
      sm[r] += e;
    }
  #pragma unroll
  for (int r = 0; r < 4; ++r) {
    #pragma unroll
    for (int off = 1; off < 16; off <<= 1)
      sm[r] += __shfl_xor(sm[r], off, 64);
    sm[r] = 1.0f / sm[r];
  }
  float* obase = attn + ((size_t)bh * 512 + srow) * 512 + l15;
  #pragma unroll
  for (int r = 0; r < 4; ++r)
    #pragma unroll
    for (int tile = 0; tile < 32; ++tile)
      __builtin_nontemporal_store(acc[tile][r] * sm[r], &obase[(size_t)r * 512 + tile * 16]);
}

extern "C" void kernel_launch(void* const* d_in, const int* in_sizes, int n_in,
                              void* d_out, int out_size, void* d_ws, size_t ws_size,
                              hipStream_t stream) {
  const float* query    = (const float*)d_in[0];
  const float* key_in   = (const float*)d_in[1];
  const int*   mask     = (const int*)d_in[2];
  const float* aspect   = (const float*)d_in[3];
  const int*   a_ids    = (const int*)d_in[4];
  const float* Wq       = (const float*)d_in[5];
  const float* bq       = (const float*)d_in[6];
  const float* Wk       = (const float*)d_in[7];
  const float* bk       = (const float*)d_in[8];
  const float* Wd       = (const float*)d_in[9];
  const float* bd       = (const float*)d_in[10];
  const float* weight_m = (const float*)d_in[11];
  const float* bias_m   = (const float*)d_in[12];

  float* out_asc  = (float*)d_out;
  float* out_attn = out_asc + 33554432ull;  // B*H*S*S

  char* ws = (char*)d_ws;
  unsigned short* Aq   = (unsigned short*)(ws);                 // 8 MB  bf16 query
  unsigned short* Ak   = (unsigned short*)(ws + 8388608);       // 8 MB  bf16 key_in
  unsigned short* Wqt  = (unsigned short*)(ws + 16777216);      // 2 MB  bf16 Wq^T
  unsigned short* Wkt  = (unsigned short*)(ws + 18874368);      // 2 MB  bf16 Wk^T
  unsigned short* qbuf = (unsigned short*)(ws + 20971520);      // 8 MB  q (B,H,S,DK)
  unsigned short* kbuf = (unsigned short*)(ws + 29360128);      // 8 MB  k (B,H,S,DK)
  float* u   = (float*)(ws + 37748736);                         // 512 KB
  float* c   = (float*)(ws + 38273024);                         // 4 KB pad
  float* v   = (float*)(ws + 38277120);                         // 256 KB
  unsigned long long* mb = (unsigned long long*)(ws + 38539264);// 256 KB bitmask

  prep_fused_kernel<<<dim3(10752), dim3(256), 0, stream>>>(
      query, key_in, Wq, Wk, aspect, Wd, bd, weight_m, bk, mask,
      Aq, Ak, Wqt, Wkt, u, c, mb);
  gemm_kernel<<<dim3(32, 8, 2), dim3(256), 0, stream>>>(Aq, Ak, Wqt, Wkt, bq, bk, qbuf, kbuf);
  v_kernel<<<dim3(64, 8), dim3(256), 0, stream>>>(key_in, u, c, bias_m, v);
  asc_kernel<<<dim3(32768), dim3(256), 0, stream>>>(v, a_ids, out_asc);
  attn_kernel<<<dim3(128, 8), dim3(256), 0, stream>>>(qbuf, kbuf, (const unsigned*)mb, out_attn);
}